// Round 10
// baseline (400.603 us; speedup 1.0000x reference)
//
#include <hip/hip_runtime.h>
#include <hip/hip_bf16.h>

typedef __hip_bfloat16 bf16;

__device__ __forceinline__ float b2f(bf16 v) { return __bfloat162float(v); }
__device__ __forceinline__ bf16  f2b(float v){ return __float2bfloat16(v); }
__device__ __forceinline__ float uplo(unsigned u){ return __uint_as_float(u << 16); }
__device__ __forceinline__ float uphi(unsigned u){ return __uint_as_float(u & 0xFFFF0000u); }
__device__ __forceinline__ unsigned pk2(float a, float b){
    bf16 ha = f2b(a), hb = f2b(b);
    unsigned short ua = *reinterpret_cast<unsigned short*>(&ha);
    unsigned short ub = *reinterpret_cast<unsigned short*>(&hb);
    return (unsigned)ua | ((unsigned)ub << 16);
}

// dtype-flexible loads (flags resolved at runtime by sniff_kernel; branches are uniform)
__device__ __forceinline__ float loadF(const void* p, int i, int isf32) {
    return isf32 ? ((const float*)p)[i] : b2f(((const bf16*)p)[i]);
}
__device__ __forceinline__ int loadI(const void* p, long long i, int isi64) {
    return isi64 ? (int)((const long long*)p)[i] : ((const int*)p)[i];
}

#define NSBW 512      // super-bucket width (nodes)
#define SBSH 9        // log2(NSBW)
#define CHUNK_A 4096  // edges per pass-A block
#define BCAP 12288    // pass-B LDS edge capacity (48 KB)

// ---------------------------------------------------------------- dtype sniff
__global__ void sniff_kernel(const void* xv, const void* eiv, int* flags) {
    int lane = threadIdx.x;                       // 64 threads
    const bf16* xb = (const bf16*)xv;
    int big = 0;
#pragma unroll
    for (int k = 0; k < 4; k++) {
        float v = fabsf(b2f(xb[lane * 4 + k]));
        if (v > 1e6f) big = 1;
    }
    unsigned long long bigmask = __ballot(big);
    const int* e32 = (const int*)eiv;
    int nz = (lane < 32) ? (e32[2 * lane + 1] != 0) : 0;
    unsigned long long nzmask = __ballot(nz);
    if (lane == 0) {
        flags[0] = (__popcll(bigmask) >= 8) ? 1 : 0;
        flags[1] = (nzmask == 0ULL) ? 1 : 0;
    }
}

// ---------------------------------------------------------------- fills
__global__ void zero_f32(float* __restrict__ p, long long cnt) {
    long long i = (long long)blockIdx.x * blockDim.x + threadIdx.x;
    if (i < cnt) p[i] = 0.f;
}
__global__ void zero_i32(int* __restrict__ p, long long cnt) {
    long long i = (long long)blockIdx.x * blockDim.x + threadIdx.x;
    if (i < cnt) p[i] = 0;
}

// ================================================================ Pass A1: super-bucket counts (padded stride-16)
__global__ void sb_count(const void* ei, int* __restrict__ sbcnt, int E, int n,
                         const int* __restrict__ flags) {
    __shared__ int h[512];
    int tid = threadIdx.x;                        // 256
    h[tid] = 0; h[tid + 256] = 0;
    __syncthreads();
    int idf = flags[1];
    long long bs = (long long)blockIdx.x * CHUNK_A;
#pragma unroll 4
    for (int it = 0; it < CHUNK_A / 256; it++) {
        long long e = bs + it * 256 + tid;
        if (e < E) {
            int s = loadI(ei, e, idf);
            int d = loadI(ei, (long long)E + e, idf);
            if ((unsigned)s < (unsigned)n && (unsigned)d < (unsigned)n)
                atomicAdd(&h[d >> SBSH], 1);
        }
    }
    __syncthreads();
    if (h[tid]) atomicAdd(&sbcnt[tid * 16], h[tid]);
    if (h[tid + 256]) atomicAdd(&sbcnt[(tid + 256) * 16], h[tid + 256]);
}

// ================================================================ scan over NSB (<=512) bins; init sbcur
__global__ void sb_scan(const int* __restrict__ sbcnt, int* __restrict__ sboff,
                        int* __restrict__ sbcur, int NSB) {
    __shared__ int lds[512];
    int t = threadIdx.x;                          // 512
    int v = (t < NSB) ? sbcnt[t * 16] : 0;
    lds[t] = v; __syncthreads();
    for (int off = 1; off < 512; off <<= 1) {
        int tv = (t >= off) ? lds[t - off] : 0;
        __syncthreads();
        lds[t] += tv;
        __syncthreads();
    }
    if (t < NSB) { int ex = lds[t] - v; sboff[t] = ex; sbcur[t * 16] = ex; }
    if (t == 0) sboff[NSB] = lds[511];            // grand total
}

// ================================================================ Pass A2: run-reserved scatter into tmp (packed)
__global__ void sb_scatter(const void* ei, int* __restrict__ sbcur,
                           unsigned* __restrict__ tmp, int E, int n,
                           const int* __restrict__ flags) {
    __shared__ int h[512];
    __shared__ int base[512];
    int tid = threadIdx.x;                        // 256
    h[tid] = 0; h[tid + 256] = 0;
    __syncthreads();
    int idf = flags[1];
    long long bs = (long long)blockIdx.x * CHUNK_A;
    // phase 1: local count
#pragma unroll 4
    for (int it = 0; it < CHUNK_A / 256; it++) {
        long long e = bs + it * 256 + tid;
        if (e < E) {
            int s = loadI(ei, e, idf);
            int d = loadI(ei, (long long)E + e, idf);
            if ((unsigned)s < (unsigned)n && (unsigned)d < (unsigned)n)
                atomicAdd(&h[d >> SBSH], 1);
        }
    }
    __syncthreads();
    // phase 2: reserve contiguous runs (padded global cursors), reset own counters
    int c0 = h[tid];       if (c0) base[tid] = atomicAdd(&sbcur[tid * 16], c0);
    int c1 = h[tid + 256]; if (c1) base[tid + 256] = atomicAdd(&sbcur[(tid + 256) * 16], c1);
    h[tid] = 0; h[tid + 256] = 0;
    __syncthreads();
    // phase 3: rank + write (runs -> near-full-line writes)
#pragma unroll 4
    for (int it = 0; it < CHUNK_A / 256; it++) {
        long long e = bs + it * 256 + tid;
        if (e < E) {
            int s = loadI(ei, e, idf);
            int d = loadI(ei, (long long)E + e, idf);
            if ((unsigned)s < (unsigned)n && (unsigned)d < (unsigned)n) {
                int b = d >> SBSH;
                int r = atomicAdd(&h[b], 1);
                tmp[base[b] + r] = (unsigned)s | ((unsigned)(d & (NSBW - 1)) << 18);
            }
        }
    }
}

// ================================================================ Pass B: per-super-bucket exact CSR (LDS sort)
__global__ __launch_bounds__(512) void sb_sort(const unsigned* __restrict__ tmp,
                                               const int* __restrict__ sboff,
                                               int* __restrict__ rowptr, int* __restrict__ adj,
                                               int n, int NSB) {
    __shared__ unsigned buf[BCAP];                // 48 KB
    __shared__ int deg[NSBW], sc[NSBW], excl[NSBW], cur[NSBW];
    int sb = blockIdx.x, tid = threadIdx.x;       // 512 threads
    int beg = sboff[sb], end = sboff[sb + 1], len = end - beg;
    deg[tid] = 0; cur[tid] = 0;
    __syncthreads();
    bool fits = (len <= BCAP);
    for (int i = tid; i < len; i += 512) {
        unsigned p = tmp[beg + i];
        if (fits) buf[i] = p;
        atomicAdd(&deg[p >> 18], 1);
    }
    __syncthreads();
    sc[tid] = deg[tid]; __syncthreads();
    for (int off = 1; off < 512; off <<= 1) {     // Hillis-Steele inclusive scan
        int tv = (tid >= off) ? sc[tid - off] : 0;
        __syncthreads();
        sc[tid] += tv;
        __syncthreads();
    }
    excl[tid] = sc[tid] - deg[tid];
    int node = (sb << SBSH) + tid;
    if (node < n) rowptr[node] = beg + excl[tid];
    if (sb == 0 && tid == 0) rowptr[n] = sboff[NSB];
    __syncthreads();
    for (int i = tid; i < len; i += 512) {
        unsigned p = fits ? buf[i] : tmp[beg + i];
        int dl = (int)(p >> 18);
        int pos = excl[dl] + atomicAdd(&cur[dl], 1);
        adj[beg + pos] = (int)(p & 0x3FFFFu);     // block-private window: ~1x write amp
    }
}

// dinv + packed bf16 z row (16 B): [z0..z5, dinv, 0]
__global__ void prep2_kernel(const int* __restrict__ rowptr, const void* xv,
                             float* __restrict__ dinv, uint4* __restrict__ zb,
                             int n, const int* __restrict__ flags) {
    int i = blockIdx.x * blockDim.x + threadIdx.x;
    if (i >= n) return;
    int xf = flags[0];
    int deg = rowptr[i + 1] - rowptr[i];
    float dv = rsqrtf((float)deg + 1.0f);
    dinv[i] = dv;
    float z0 = loadF(xv, i * 6 + 0, xf) * dv, z1 = loadF(xv, i * 6 + 1, xf) * dv;
    float z2 = loadF(xv, i * 6 + 2, xf) * dv, z3 = loadF(xv, i * 6 + 3, xf) * dv;
    float z4 = loadF(xv, i * 6 + 4, xf) * dv, z5 = loadF(xv, i * 6 + 5, xf) * dv;
    uint4 r;
    r.x = pk2(z0, z1); r.y = pk2(z2, z3); r.z = pk2(z4, z5); r.w = pk2(dv, 0.f);
    zb[i] = r;
}

// ================================================================ layer 1: one node per 32-group, 32 edges/iter, 16B bf16 z rows
__global__ void gcn1_kernel(const int* __restrict__ rowptr, const int* __restrict__ adj,
                            const uint4* __restrict__ zb, const float* __restrict__ dinv,
                            const void* W1v, const void* b1v, const void* W2v,
                            bf16* __restrict__ Y2lo, bf16* __restrict__ Y2hi,
                            int n, const int* __restrict__ flags) {
    __shared__ float sW1[192];
    __shared__ float sW2[1024];
    __shared__ float sb1[32];
    int xf = flags[0];
    int tid = threadIdx.x;
    if (tid < 192) sW1[tid] = loadF(W1v, tid, xf);
    for (int i = tid; i < 1024; i += 256) sW2[i] = loadF(W2v, i, xf);
    if (tid < 32) sb1[tid] = loadF(b1v, tid, xf);
    __syncthreads();
    long long t = (long long)blockIdx.x * blockDim.x + tid;
    int node = (int)(t >> 5), j = (int)(t & 31);
    if (node >= n) return;
    int base = rowptr[node], end = rowptr[node + 1];
    float a0 = 0, a1 = 0, a2 = 0, a3 = 0, a4 = 0, a5 = 0;
    for (int i0 = base; i0 < end; i0 += 32) {
        int idx = i0 + j;
        if (idx < end) {
            uint4 v = zb[adj[idx]];
            a0 += uplo(v.x); a1 += uphi(v.x);
            a2 += uplo(v.y); a3 += uphi(v.y);
            a4 += uplo(v.z); a5 += uphi(v.z);
        }
    }
#pragma unroll
    for (int off = 1; off <= 16; off <<= 1) {
        a0 += __shfl_xor(a0, off, 32); a1 += __shfl_xor(a1, off, 32);
        a2 += __shfl_xor(a2, off, 32); a3 += __shfl_xor(a3, off, 32);
        a4 += __shfl_xor(a4, off, 32); a5 += __shfl_xor(a5, off, 32);
    }
    uint4 zs = zb[node];
    a0 += uplo(zs.x); a1 += uphi(zs.x); a2 += uplo(zs.y);
    a3 += uphi(zs.y); a4 += uplo(zs.z); a5 += uphi(zs.z);
    float dv = dinv[node];
    float v = a0 * sW1[j];
    v = fmaf(a1, sW1[32 + j], v);
    v = fmaf(a2, sW1[64 + j], v);
    v = fmaf(a3, sW1[96 + j], v);
    v = fmaf(a4, sW1[128 + j], v);
    v = fmaf(a5, sW1[160 + j], v);
    float h = fmaxf(fmaf(dv, v, sb1[j]), 0.f);
    float y2 = 0.f;
#pragma unroll
    for (int kk = 0; kk < 32; kk++) y2 = fmaf(__shfl(h, kk, 32), sW2[kk * 32 + j], y2);
    y2 *= dv;
    if (j < 16) Y2lo[(size_t)node * 16 + j] = f2b(y2);
    else        Y2hi[(size_t)node * 16 + (j - 16)] = f2b(y2);
}

// ================================================================ layer 2 half-pass: gather 32B half-rows (L2-resident), write features half
__global__ void gcn2_half(const int* __restrict__ rowptr, const int* __restrict__ adj,
                          const uint4* __restrict__ Yh, const float* __restrict__ dinv,
                          const void* b2v, float* __restrict__ outF,
                          int n, int halfbase, const int* __restrict__ flags) {
    int xf = flags[0];
    long long t = (long long)blockIdx.x * blockDim.x + threadIdx.x;
    int node = (int)(t >> 5), j = (int)(t & 31);
    if (node >= n) return;
    int p = j & 1;
    int base = rowptr[node], end = rowptr[node + 1];
    float a0 = 0, a1 = 0, a2 = 0, a3 = 0, a4 = 0, a5 = 0, a6 = 0, a7 = 0;
    for (int i0 = base; i0 < end; i0 += 16) {
        int idx = i0 + (j >> 1);
        if (idx < end) {
            uint4 v = Yh[(size_t)adj[idx] * 2 + p];
            a0 += uplo(v.x); a1 += uphi(v.x); a2 += uplo(v.y); a3 += uphi(v.y);
            a4 += uplo(v.z); a5 += uphi(v.z); a6 += uplo(v.w); a7 += uphi(v.w);
        }
    }
#pragma unroll
    for (int off = 2; off <= 16; off <<= 1) {     // keep parity classes separate
        a0 += __shfl_xor(a0, off, 32); a1 += __shfl_xor(a1, off, 32);
        a2 += __shfl_xor(a2, off, 32); a3 += __shfl_xor(a3, off, 32);
        a4 += __shfl_xor(a4, off, 32); a5 += __shfl_xor(a5, off, 32);
        a6 += __shfl_xor(a6, off, 32); a7 += __shfl_xor(a7, off, 32);
    }
    if (j < 2) {                                  // lane0: dims 0-7 of half; lane1: dims 8-15
        uint4 sv = Yh[(size_t)node * 2 + p];
        a0 += uplo(sv.x); a1 += uphi(sv.x); a2 += uplo(sv.y); a3 += uphi(sv.y);
        a4 += uplo(sv.z); a5 += uphi(sv.z); a6 += uplo(sv.w); a7 += uphi(sv.w);
        float dv = dinv[node];
        int bo = halfbase + p * 8;
        float4 w0, w1;
        w0.x = fmaf(dv, a0, loadF(b2v, bo + 0, xf));
        w0.y = fmaf(dv, a1, loadF(b2v, bo + 1, xf));
        w0.z = fmaf(dv, a2, loadF(b2v, bo + 2, xf));
        w0.w = fmaf(dv, a3, loadF(b2v, bo + 3, xf));
        w1.x = fmaf(dv, a4, loadF(b2v, bo + 4, xf));
        w1.y = fmaf(dv, a5, loadF(b2v, bo + 5, xf));
        w1.z = fmaf(dv, a6, loadF(b2v, bo + 6, xf));
        w1.w = fmaf(dv, a7, loadF(b2v, bo + 7, xf));
        float* dst = outF + (size_t)node * 32 + bo;
        *(float4*)dst = w0;
        *(float4*)(dst + 4) = w1;
    }
}

// ================================================================ heads: node-parallel, reads features sequentially
// out layout (f32): [logits n][normals 3n][uvs 3n][features 32n]
__global__ void head_kernel(const void* Wt1v, const void* bt1v, const void* Wt2v, const void* bt2v,
                            const void* Wa1v, const void* ba1v, const void* Wa2v, const void* ba2v,
                            float* __restrict__ out, int n, const int* __restrict__ flags) {
    __shared__ float sWt1[512], sWa1[512], sWt2[16], sWa2[96];
    __shared__ float sbt1[16], sba1[16], sba2[6];
    __shared__ float sbt2;
    int xf = flags[0];
    int tid = threadIdx.x;
    for (int i = tid; i < 512; i += blockDim.x) { sWt1[i] = loadF(Wt1v, i, xf); sWa1[i] = loadF(Wa1v, i, xf); }
    if (tid < 96) sWa2[tid] = loadF(Wa2v, tid, xf);
    if (tid < 16) { sWt2[tid] = loadF(Wt2v, tid, xf); sbt1[tid] = loadF(bt1v, tid, xf); sba1[tid] = loadF(ba1v, tid, xf); }
    if (tid < 6) sba2[tid] = loadF(ba2v, tid, xf);
    if (tid == 0) sbt2 = loadF(bt2v, 0, xf);
    __syncthreads();
    long long t = (long long)blockIdx.x * blockDim.x + tid;
    int node = (int)(t >> 5), j = (int)(t & 31);
    if (node >= n) return;
    float f = out[(size_t)n * 7 + (size_t)node * 32 + j];
    float acc = 0.f;
#pragma unroll
    for (int k = 0; k < 32; k++) {
        float fk = __shfl(f, k, 32);
        float w = (j < 16) ? sWt1[k * 16 + j] : sWa1[k * 16 + (j - 16)];
        acc = fmaf(fk, w, acc);
    }
    float u = fmaxf(acc + ((j < 16) ? sbt1[j] : sba1[j - 16]), 0.f);
    float o = 0.f;
#pragma unroll
    for (int k = 0; k < 16; k++) {
        float ut = __shfl(u, k, 32);
        float ua = __shfl(u, 16 + k, 32);
        float w = (j == 0) ? sWt2[k] : ((j < 7) ? sWa2[k * 6 + (j - 1)] : 0.f);
        o = fmaf((j == 0) ? ut : ua, w, o);
    }
    if (j == 0)      out[node] = o + sbt2;
    else if (j < 4)  out[(size_t)n     + (size_t)node * 3 + (j - 1)] = o + sba2[j - 1];
    else if (j < 7)  out[(size_t)n * 4 + (size_t)node * 3 + (j - 4)] = o + sba2[j - 1];
}

// ================================================================ fallback (round-4 scatter path)
__global__ void count_kernel(const void* ei, float* __restrict__ deg, int E, int n,
                             const int* __restrict__ flags) {
    int e = blockIdx.x * blockDim.x + threadIdx.x;
    if (e >= E) return;
    int d = loadI(ei, (long long)E + e, flags[1]);
    if ((unsigned)d < (unsigned)n) atomicAdd(&deg[d], 1.0f);
}
__global__ void dinv_kernel(float* __restrict__ dinv, int n) {
    int i = blockIdx.x * blockDim.x + threadIdx.x;
    if (i < n) dinv[i] = rsqrtf(dinv[i] + 1.0f);
}
__global__ void scatter1_kernel(const void* ei, const void* xv, const void* W1v,
                                const float* __restrict__ dinv, float* __restrict__ A,
                                int E, int n, const int* __restrict__ flags) {
    __shared__ float sW1[6 * 32];
    int xf = flags[0], idf = flags[1];
    int tid = threadIdx.x;
    if (tid < 192) sW1[tid] = loadF(W1v, tid, xf);
    __syncthreads();
    long long t = (long long)blockIdx.x * blockDim.x + tid;
    int e = (int)(t >> 5), j = (int)(t & 31);
    if (e >= E) return;
    int s = loadI(ei, e, idf);
    int d = loadI(ei, (long long)E + e, idf);
    if ((unsigned)s >= (unsigned)n || (unsigned)d >= (unsigned)n) return;
    float dv = dinv[s];
    float y = 0.f;
#pragma unroll
    for (int k = 0; k < 6; k++) y = fmaf(loadF(xv, s * 6 + k, xf), sW1[k * 32 + j], y);
    atomicAdd(&A[(size_t)d * 32 + j], y * dv);
}
__global__ void fused_mid_kernel(const float* __restrict__ A, const void* xv,
                                 const float* __restrict__ dinv,
                                 const void* W1v, const void* b1v, const void* W2v,
                                 float* __restrict__ Yf, int n, const int* __restrict__ flags) {
    __shared__ float sW1[6 * 32];
    __shared__ float sW2[32 * 32];
    __shared__ float sb1[32];
    int xf = flags[0];
    int tid = threadIdx.x;
    if (tid < 192) sW1[tid] = loadF(W1v, tid, xf);
    for (int i = tid; i < 32 * 32; i += blockDim.x) sW2[i] = loadF(W2v, i, xf);
    if (tid < 32) sb1[tid] = loadF(b1v, tid, xf);
    __syncthreads();
    long long t = (long long)blockIdx.x * blockDim.x + tid;
    int node = (int)(t >> 5), j = (int)(t & 31);
    if (node >= n) return;
    float dv = dinv[node];
    float xw = 0.f;
#pragma unroll
    for (int k = 0; k < 6; k++) xw = fmaf(loadF(xv, node * 6 + k, xf), sW1[k * 32 + j], xw);
    float h = fmaxf(dv * A[t] + dv * dv * xw + sb1[j], 0.f);
    float y2 = 0.f;
#pragma unroll
    for (int k = 0; k < 32; k++) y2 = fmaf(__shfl(h, k, 32), sW2[k * 32 + j], y2);
    Yf[t] = y2 * dv;
}
__global__ void scatter2_kernel(const void* ei, const float* __restrict__ Yf,
                                float* __restrict__ A, int E, int n,
                                const int* __restrict__ flags) {
    int idf = flags[1];
    long long t = (long long)blockIdx.x * blockDim.x + threadIdx.x;
    int e = (int)(t >> 5), j = (int)(t & 31);
    if (e >= E) return;
    int s = loadI(ei, e, idf);
    int d = loadI(ei, (long long)E + e, idf);
    if ((unsigned)s >= (unsigned)n || (unsigned)d >= (unsigned)n) return;
    atomicAdd(&A[(size_t)d * 32 + j], Yf[(size_t)s * 32 + j]);
}
__global__ void out_kernel(const float* __restrict__ A, const float* __restrict__ dinv,
                           const void* b2v,
                           const void* Wt1v, const void* bt1v, const void* Wt2v, const void* bt2v,
                           const void* Wa1v, const void* ba1v, const void* Wa2v, const void* ba2v,
                           float* __restrict__ out, int n, const int* __restrict__ flags) {
    __shared__ float sWt1[32 * 16], sWa1[32 * 16], sWt2[16], sWa2[16 * 6];
    __shared__ float sbt1[16], sba1[16], sba2[6], sb2[32];
    __shared__ float sbt2;
    int xf = flags[0];
    int tid = threadIdx.x;
    for (int i = tid; i < 32 * 16; i += blockDim.x) { sWt1[i] = loadF(Wt1v, i, xf); sWa1[i] = loadF(Wa1v, i, xf); }
    for (int i = tid; i < 16 * 6; i += blockDim.x) sWa2[i] = loadF(Wa2v, i, xf);
    if (tid < 16) { sWt2[tid] = loadF(Wt2v, tid, xf); sbt1[tid] = loadF(bt1v, tid, xf); sba1[tid] = loadF(ba1v, tid, xf); }
    if (tid < 32) sb2[tid] = loadF(b2v, tid, xf);
    if (tid < 6) sba2[tid] = loadF(ba2v, tid, xf);
    if (tid == 0) sbt2 = loadF(bt2v, 0, xf);
    __syncthreads();
    long long t = (long long)blockIdx.x * blockDim.x + tid;
    int node = (int)(t >> 5), j = (int)(t & 31);
    if (node >= n) return;
    float* Yf = out + (size_t)n * 7;
    float dv = dinv[node];
    float f = dv * (A[t] + Yf[t]) + sb2[j];
    Yf[t] = f;
    float acc = 0.f;
#pragma unroll
    for (int k = 0; k < 32; k++) {
        float fk = __shfl(f, k, 32);
        float w = (j < 16) ? sWt1[k * 16 + j] : sWa1[k * 16 + (j - 16)];
        acc = fmaf(fk, w, acc);
    }
    float u = fmaxf(acc + ((j < 16) ? sbt1[j] : sba1[j - 16]), 0.f);
    float o = 0.f;
#pragma unroll
    for (int k = 0; k < 16; k++) {
        float ut = __shfl(u, k, 32);
        float ua = __shfl(u, 16 + k, 32);
        float w = (j == 0) ? sWt2[k] : ((j < 7) ? sWa2[k * 6 + (j - 1)] : 0.f);
        o = fmaf((j == 0) ? ut : ua, w, o);
    }
    if (j == 0)      out[node] = o + sbt2;
    else if (j < 4)  out[(size_t)n     + (size_t)node * 3 + (j - 1)] = o + sba2[j - 1];
    else if (j < 7)  out[(size_t)n * 4 + (size_t)node * 3 + (j - 4)] = o + sba2[j - 1];
}

extern "C" void kernel_launch(void* const* d_in, const int* in_sizes, int n_in,
                              void* d_out, int out_size, void* d_ws, size_t ws_size,
                              hipStream_t stream) {
    const void* x   = d_in[0];
    const void* ei  = d_in[1];
    const void* W1  = d_in[2];
    const void* b1  = d_in[3];
    const void* W2  = d_in[4];
    const void* b2  = d_in[5];
    const void* Wt1 = d_in[6];
    const void* bt1 = d_in[7];
    const void* Wt2 = d_in[8];
    const void* bt2 = d_in[9];
    const void* Wa1 = d_in[10];
    const void* ba1 = d_in[11];
    const void* Wa2 = d_in[12];
    const void* ba2 = d_in[13];

    int n = in_sizes[0] / 6;          // 150000
    int E = in_sizes[1] / 2;          // 2400000

    const int B = 256;
    float* out = (float*)d_out;
    char* ws = (char*)d_ws;

    // ---------------- workspace (4B words) ----------------
    int NSB = (n + NSBW - 1) >> SBSH;              // super-buckets (<=512 when n<=2^18)
    size_t nw  = (size_t)((n + 63) & ~63);
    size_t Ew  = (size_t)((E + 63) & ~63);
    size_t Mw  = (16 * nw > Ew) ? 16 * nw : Ew;    // union(tmp, Y2lo+Y2hi)
    size_t w_sbc = 0;                              // sbcnt padded x16: 8192
    size_t w_sbo = 8192;                           // sboff: 513 -> 576
    size_t w_scu = 8192 + 576;                     // sbcur padded x16: 8192
    size_t w_flg = w_scu + 8192;
    size_t w_row = w_flg + 64;                     // rowptr n+1
    size_t w_div = w_row + nw + 64;
    size_t w_zb  = w_div + nw;                     // zb: n x 16B (4 words)
    size_t w_un  = w_zb + 4 * nw;                  // union: tmp (build) then Y2lo|Y2hi
    size_t w_adj = w_un + Mw;
    size_t need  = (w_adj + Ew) * 4;

    if (ws_size >= need && n <= (1 << 18)) {
        int*      sbcnt = (int*)(ws + w_sbc * 4);
        int*      sboff = (int*)(ws + w_sbo * 4);
        int*      sbcur = (int*)(ws + w_scu * 4);
        int*      flags = (int*)(ws + w_flg * 4);
        int*      rowptr= (int*)(ws + w_row * 4);
        float*    dinv  = (float*)(ws + w_div * 4);
        uint4*    zb    = (uint4*)(ws + w_zb * 4);
        unsigned* tmp   = (unsigned*)(ws + w_un * 4);
        bf16*     Y2lo  = (bf16*)(ws + w_un * 4);
        bf16*     Y2hi  = (bf16*)(ws + (w_un + 8 * nw) * 4);
        int*      adj   = (int*)(ws + w_adj * 4);

        int grid_a = (int)(((long long)E + CHUNK_A - 1) / CHUNK_A);
        int grid_nodes32 = (int)(((long long)n * 32 + B - 1) / B);

        sniff_kernel<<<1, 64, 0, stream>>>(x, ei, flags);
        zero_i32<<<(8192 * 2 + 576 + B - 1) / B, B, 0, stream>>>(sbcnt, 8192 * 2 + 576);
        sb_count<<<grid_a, B, 0, stream>>>(ei, sbcnt, E, n, flags);
        sb_scan<<<1, 512, 0, stream>>>(sbcnt, sboff, sbcur, NSB);
        sb_scatter<<<grid_a, B, 0, stream>>>(ei, sbcur, tmp, E, n, flags);
        sb_sort<<<NSB, 512, 0, stream>>>(tmp, sboff, rowptr, adj, n, NSB);
        prep2_kernel<<<(n + B - 1) / B, B, 0, stream>>>(rowptr, x, dinv, zb, n, flags);
        gcn1_kernel<<<grid_nodes32, B, 0, stream>>>(rowptr, adj, zb, dinv, W1, b1, W2,
                                                    Y2lo, Y2hi, n, flags);
        gcn2_half<<<grid_nodes32, B, 0, stream>>>(rowptr, adj, (const uint4*)Y2lo, dinv, b2,
                                                  out + (size_t)n * 7, n, 0, flags);
        gcn2_half<<<grid_nodes32, B, 0, stream>>>(rowptr, adj, (const uint4*)Y2hi, dinv, b2,
                                                  out + (size_t)n * 7, n, 16, flags);
        head_kernel<<<grid_nodes32, B, 0, stream>>>(Wt1, bt1, Wt2, bt2, Wa1, ba1, Wa2, ba2,
                                                    out, n, flags);
        return;
    }

    // ---------------- fallback: round-4 scatter path ----------------
    size_t n_pad = (size_t)((n + 63) & ~63);
    float* A     = (float*)ws;
    float* dinvF = (float*)(ws + (size_t)32 * n * 4);
    int* flagsF  = (int*)(ws + ((size_t)32 * n + n_pad) * 4);
    float* Yf    = out + (size_t)n * 7;

    long long zcnt = (long long)32 * n + (long long)n_pad;
    int grid_zero  = (int)((zcnt + B - 1) / B);
    int grid_zeroA = (int)(((long long)32 * n + B - 1) / B);
    int grid_nodes = (int)(((long long)n * 32 + B - 1) / B);
    int grid_edges = (int)(((long long)E * 32 + B - 1) / B);

    sniff_kernel<<<1, 64, 0, stream>>>(x, ei, flagsF);
    zero_f32<<<grid_zero, B, 0, stream>>>(A, zcnt);
    count_kernel<<<(E + B - 1) / B, B, 0, stream>>>(ei, dinvF, E, n, flagsF);
    dinv_kernel<<<(n + B - 1) / B, B, 0, stream>>>(dinvF, n);
    scatter1_kernel<<<grid_edges, B, 0, stream>>>(ei, x, W1, dinvF, A, E, n, flagsF);
    fused_mid_kernel<<<grid_nodes, B, 0, stream>>>(A, x, dinvF, W1, b1, W2, Yf, n, flagsF);
    zero_f32<<<grid_zeroA, B, 0, stream>>>(A, (long long)32 * n);
    scatter2_kernel<<<grid_edges, B, 0, stream>>>(ei, Yf, A, E, n, flagsF);
    out_kernel<<<grid_nodes, B, 0, stream>>>(A, dinvF, b2, Wt1, bt1, Wt2, bt2,
                                             Wa1, ba1, Wa2, ba2, out, n, flagsF);
}